// Round 8
// baseline (421.968 us; speedup 1.0000x reference)
//
#include <hip/hip_runtime.h>
#include <hip/hip_bf16.h>

#define DIM 4096
#define HROWS 54
#define HSZ (54 * 4096)
#define SPLITK 16
#define KSLICE 256

typedef __attribute__((ext_vector_type(4))) float  f32x4;
typedef __attribute__((ext_vector_type(8))) short  s16x8;
typedef __attribute__((ext_vector_type(4))) short  s16x4;

__device__ __forceinline__ short f2bf(float f) {
    union { __hip_bfloat16 h; short s; } u;
    u.h = __float2bfloat16(f);
    return u.s;
}
__device__ __forceinline__ float bf2f(short s) {
    union { __hip_bfloat16 h; short s; } u;
    u.s = s;
    return __bfloat162float(u.h);
}
__device__ __forceinline__ float leaky(float x) { return x > 0.f ? x : 0.01f * x; }

__device__ __forceinline__ void split8(const f32x4& c0, const f32x4& c1,
                                       s16x8& h, s16x8& l) {
#pragma unroll
    for (int j = 0; j < 4; ++j) {
        short h0 = f2bf(c0[j]); h[j]     = h0; l[j]     = f2bf(c0[j] - bf2f(h0));
        short h1 = f2bf(c1[j]); h[4 + j] = h1; l[4 + j] = f2bf(c1[j] - bf2f(h1));
    }
}

// ---------------------------------------------------------------------------
// prep: bf16 split of concept_embed (padded to 64 rows), zero pads, trig tables
// ---------------------------------------------------------------------------
__global__ __launch_bounds__(256) void prep_g(const float* __restrict__ ce,
                                              const float* __restrict__ edge,
                                              short* __restrict__ xh, short* __restrict__ xl,
                                              short* __restrict__ hbh, short* __restrict__ hbl,
                                              float* __restrict__ er, float* __restrict__ ei)
{
    const int idx = blockIdx.x * 256 + threadIdx.x;
    const int row = idx >> 12;
    if (row < HROWS) {
        const float v = ce[idx];
        const short h = f2bf(v);
        xh[idx] = h; xl[idx] = f2bf(v - bf2f(h));
    } else {
        xh[idx] = 0; xl[idx] = 0; hbh[idx] = 0; hbl[idx] = 0;
    }
    if (idx < 3 * 2048) {
        const float e = edge[idx];
        er[idx] = cosf(e);
        ei[idx] = sinf(e);
    }
}

// ---------------------------------------------------------------------------
// GEMM v5: batch-issue, no mixed-wait poisoning of the in-order vmcnt queue.
// out[m,n] = sum_k A[m,k]*W[n,k]. A bf16 hi/lo [64][4096] (L2-resident),
// W f32 streamed (HBM). grid = 64 nb x 16 ks = 1024 blocks, KSLICE=256,
// 4 kb-steps fully unrolled. Issue: [16 W loads][32 A loads kb01] SB
// [compute kb0,kb1] SB [32 A loads kb23] SB [compute kb2,kb3].
// ---------------------------------------------------------------------------
__global__ __launch_bounds__(256, 2) void gemm_g(const short* __restrict__ Ah,
                                                 const short* __restrict__ Al,
                                                 const float* __restrict__ W,
                                                 float* __restrict__ outp)
{
    const int tid  = threadIdx.x;
    const int lane = tid & 63;
    const int wv   = tid >> 6;
    const int nb   = blockIdx.x & 63;
    const int ks   = blockIdx.x >> 6;    // 0..15
    const int l15  = lane & 15;
    const int lk8  = lane >> 4;

    const int ncol = nb * 64 + wv * 16 + l15;
    const int k0   = ks * KSLICE + lk8 * 8;
    const float* wp = W + (size_t)ncol * DIM + k0;

    const short* ah0 = Ah + (size_t)(0 * 16 + l15) * DIM + k0;
    const short* ah1 = Ah + (size_t)(1 * 16 + l15) * DIM + k0;
    const short* ah2 = Ah + (size_t)(2 * 16 + l15) * DIM + k0;
    const short* ah3 = Ah + (size_t)(3 * 16 + l15) * DIM + k0;
    const short* al0 = Al + (size_t)(0 * 16 + l15) * DIM + k0;
    const short* al1 = Al + (size_t)(1 * 16 + l15) * DIM + k0;
    const short* al2 = Al + (size_t)(2 * 16 + l15) * DIM + k0;
    const short* al3 = Al + (size_t)(3 * 16 + l15) * DIM + k0;

    f32x4 acc0 = {0.f,0.f,0.f,0.f}, acc1 = {0.f,0.f,0.f,0.f};
    f32x4 acc2 = {0.f,0.f,0.f,0.f}, acc3 = {0.f,0.f,0.f,0.f};

// 4 W vectors for one kb (64 k-elems: two kk halves)
#define WL(P, KB)                                                            \
    const f32x4 P##0 = *(const f32x4*)(wp + (KB)*64);                        \
    const f32x4 P##1 = *(const f32x4*)(wp + (KB)*64 + 4);                    \
    const f32x4 P##2 = *(const f32x4*)(wp + (KB)*64 + 32);                   \
    const f32x4 P##3 = *(const f32x4*)(wp + (KB)*64 + 36);

// 16 A vectors (hi+lo, 4 m-tiles, both kk halves) for one kb
#define ALD(P, KB)                                                           \
    const s16x8 P##h0a = *(const s16x8*)(ah0 + (KB)*64);                     \
    const s16x8 P##h1a = *(const s16x8*)(ah1 + (KB)*64);                     \
    const s16x8 P##h2a = *(const s16x8*)(ah2 + (KB)*64);                     \
    const s16x8 P##h3a = *(const s16x8*)(ah3 + (KB)*64);                     \
    const s16x8 P##l0a = *(const s16x8*)(al0 + (KB)*64);                     \
    const s16x8 P##l1a = *(const s16x8*)(al1 + (KB)*64);                     \
    const s16x8 P##l2a = *(const s16x8*)(al2 + (KB)*64);                     \
    const s16x8 P##l3a = *(const s16x8*)(al3 + (KB)*64);                     \
    const s16x8 P##h0b = *(const s16x8*)(ah0 + (KB)*64 + 32);                \
    const s16x8 P##h1b = *(const s16x8*)(ah1 + (KB)*64 + 32);                \
    const s16x8 P##h2b = *(const s16x8*)(ah2 + (KB)*64 + 32);                \
    const s16x8 P##h3b = *(const s16x8*)(ah3 + (KB)*64 + 32);                \
    const s16x8 P##l0b = *(const s16x8*)(al0 + (KB)*64 + 32);                \
    const s16x8 P##l1b = *(const s16x8*)(al1 + (KB)*64 + 32);                \
    const s16x8 P##l2b = *(const s16x8*)(al2 + (KB)*64 + 32);                \
    const s16x8 P##l3b = *(const s16x8*)(al3 + (KB)*64 + 32);

#define MF(BH, BL, A0H, A1H, A2H, A3H, A0L, A1L, A2L, A3L)                   \
    acc0 = __builtin_amdgcn_mfma_f32_16x16x32_bf16(A0H, BH, acc0, 0, 0, 0);  \
    acc1 = __builtin_amdgcn_mfma_f32_16x16x32_bf16(A1H, BH, acc1, 0, 0, 0);  \
    acc2 = __builtin_amdgcn_mfma_f32_16x16x32_bf16(A2H, BH, acc2, 0, 0, 0);  \
    acc3 = __builtin_amdgcn_mfma_f32_16x16x32_bf16(A3H, BH, acc3, 0, 0, 0);  \
    acc0 = __builtin_amdgcn_mfma_f32_16x16x32_bf16(A0L, BH, acc0, 0, 0, 0);  \
    acc1 = __builtin_amdgcn_mfma_f32_16x16x32_bf16(A1L, BH, acc1, 0, 0, 0);  \
    acc2 = __builtin_amdgcn_mfma_f32_16x16x32_bf16(A2L, BH, acc2, 0, 0, 0);  \
    acc3 = __builtin_amdgcn_mfma_f32_16x16x32_bf16(A3L, BH, acc3, 0, 0, 0);  \
    acc0 = __builtin_amdgcn_mfma_f32_16x16x32_bf16(A0H, BL, acc0, 0, 0, 0);  \
    acc1 = __builtin_amdgcn_mfma_f32_16x16x32_bf16(A1H, BL, acc1, 0, 0, 0);  \
    acc2 = __builtin_amdgcn_mfma_f32_16x16x32_bf16(A2H, BL, acc2, 0, 0, 0);  \
    acc3 = __builtin_amdgcn_mfma_f32_16x16x32_bf16(A3H, BL, acc3, 0, 0, 0);

#define CK(WP, AP) do {                                                      \
    { s16x8 bh, bl; split8(WP##0, WP##1, bh, bl);                            \
      MF(bh, bl, AP##h0a, AP##h1a, AP##h2a, AP##h3a,                         \
                 AP##l0a, AP##l1a, AP##l2a, AP##l3a); }                      \
    { s16x8 bh, bl; split8(WP##2, WP##3, bh, bl);                            \
      MF(bh, bl, AP##h0b, AP##h1b, AP##h2b, AP##h3b,                         \
                 AP##l0b, AP##l1b, AP##l2b, AP##l3b); } } while (0)

    // ---- batch 0: all W, A for kb0/kb1 ----
    WL(w0_, 0) WL(w1_, 1) WL(w2_, 2) WL(w3_, 3)
    ALD(pA_, 0) ALD(pB_, 1)
    __builtin_amdgcn_sched_barrier(0);
    CK(w0_, pA_);
    CK(w1_, pB_);
    __builtin_amdgcn_sched_barrier(0);
    // ---- batch 1: A for kb2/kb3 (waits drain older W2/W3 = needed anyway) ----
    ALD(pC_, 2) ALD(pD_, 3)
    __builtin_amdgcn_sched_barrier(0);
    CK(w2_, pC_);
    CK(w3_, pD_);

#undef WL
#undef ALD
#undef MF
#undef CK

    float* op = outp + (size_t)ks * HSZ;
#pragma unroll
    for (int mt = 0; mt < 4; ++mt) {
        const f32x4 a = (mt == 0) ? acc0 : (mt == 1) ? acc1 : (mt == 2) ? acc2 : acc3;
#pragma unroll
        for (int r = 0; r < 4; ++r) {
            const int m = mt * 16 + lk8 * 4 + r;
            if (m < HROWS) op[(size_t)m * DIM + ncol] = a[r];
        }
    }
}

// ---------------------------------------------------------------------------
// p2: reduce split-K partials -> bf16 hi/lo of h + fused attention-dot partials
// ---------------------------------------------------------------------------
__global__ __launch_bounds__(256) void p2_g(const float* __restrict__ hpart,
                                            const float* __restrict__ wA,
                                            const float* __restrict__ wB,
                                            const float* __restrict__ wC,
                                            short* __restrict__ hbh, short* __restrict__ hbl,
                                            float* __restrict__ dotp)
{
    const int vb  = blockIdx.x;          // 0..215
    const int tid = threadIdx.x;
    const int i   = vb * 1024 + tid * 4;
    const int col = i & (DIM - 1);
    f32x4 s = {0.f,0.f,0.f,0.f};
#pragma unroll
    for (int sl = 0; sl < SPLITK; ++sl) s += *(const f32x4*)(hpart + (size_t)sl * HSZ + i);

    s16x4 vh, vl;
#pragma unroll
    for (int j = 0; j < 4; ++j) {
        const short h = f2bf(s[j]);
        vh[j] = h; vl[j] = f2bf(s[j] - bf2f(h));
    }
    *(s16x4*)(hbh + i) = vh;
    *(s16x4*)(hbl + i) = vl;

    float a0=0,a1=0,a2=0,a3=0,a4=0,a5=0;
#pragma unroll
    for (int j = 0; j < 4; ++j) {
        const float sv = s[j];
        const int c = col + j;
        a0 += sv * wA[c]; a1 += sv * wA[DIM + c];
        a2 += sv * wB[c]; a3 += sv * wB[DIM + c];
        a4 += sv * wC[c]; a5 += sv * wC[DIM + c];
    }
#pragma unroll
    for (int off = 32; off > 0; off >>= 1) {
        a0 += __shfl_down(a0, off); a1 += __shfl_down(a1, off);
        a2 += __shfl_down(a2, off); a3 += __shfl_down(a3, off);
        a4 += __shfl_down(a4, off); a5 += __shfl_down(a5, off);
    }
    if ((tid & 63) == 0) {
        float* d = dotp + ((size_t)vb * 4 + (tid >> 6)) * 6;
        d[0]=a0; d[1]=a1; d[2]=a2; d[3]=a3; d[4]=a4; d[5]=a5;
    }
}

// ---------------------------------------------------------------------------
// p4: reduce gemm2 split-K partials to f32 gsum
// ---------------------------------------------------------------------------
__global__ __launch_bounds__(256) void p4_g(const float* __restrict__ hpart,
                                            float* __restrict__ gsum)
{
    const int i = blockIdx.x * 1024 + threadIdx.x * 4;
    f32x4 s = {0.f,0.f,0.f,0.f};
#pragma unroll
    for (int sl = 0; sl < SPLITK; ++sl) s += *(const f32x4*)(hpart + (size_t)sl * HSZ + i);
    *(f32x4*)(gsum + i) = s;
}

// ---------------------------------------------------------------------------
// tmat: one block. Reduce dot partials, build 54x54 mixing matrix T.
// ---------------------------------------------------------------------------
__global__ __launch_bounds__(256) void tmat_g(const float* __restrict__ dotp,
                                              float* __restrict__ Tm)
{
    const int tid = threadIdx.x;
    __shared__ float ds[324];
    __shared__ float Ts[54][54];
    __shared__ float ad0[5], adc[12], ar[6], fdot3[12], fdot5[12], ddot5[5];

    for (int x = tid; x < 324; x += 256) {
        const int r = x / 6, v = x % 6;
        float s = 0.f;
#pragma unroll
        for (int u = 0; u < 16; ++u) s += dotp[(size_t)(r * 16 + u) * 6 + v];
        ds[x] = s;
    }
    for (int i = tid; i < 54 * 54; i += 256) ((float*)Ts)[i] = 0.f;
    __syncthreads();

    if (tid < 12) {                       // level if
        const int p = tid;
        const float u = ds[(6+p)*6 + 0];
        const float ss = leaky(u + ds[(6+p)*6 + 1]);
        float sc[3], mx = ss;
#pragma unroll
        for (int j = 0; j < 3; ++j) { sc[j] = leaky(u + ds[(18+3*p+j)*6 + 1]); mx = fmaxf(mx, sc[j]); }
        float e0 = expf(ss - mx), s = e0, ec[3];
#pragma unroll
        for (int j = 0; j < 3; ++j) { ec[j] = expf(sc[j] - mx); s += ec[j]; }
        const float inv = 1.f / s;
        const float a0 = e0 * inv;
        float f3 = a0 * ds[(6+p)*6 + 3];
        float f5 = a0 * ds[(6+p)*6 + 5];
        Ts[6+p][6+p] = a0;
#pragma unroll
        for (int j = 0; j < 3; ++j) {
            const float a = ec[j] * inv;
            Ts[6+p][18+3*p+j] = a;
            f3 += a * ds[(18+3*p+j)*6 + 3];
            f5 += a * ds[(18+3*p+j)*6 + 5];
        }
        fdot3[p] = f3; fdot5[p] = f5;
    }
    __syncthreads();

    if (tid < 5) {                        // level fd
        const int p = tid;
        const int cstart[5] = {0,3,5,8,10};
        const int ccnt[5]   = {3,2,3,2,2};
        const float u = ds[(1+p)*6 + 2];
        const float ss = leaky(u + ds[(1+p)*6 + 3]);
        const int n = ccnt[p], c0 = cstart[p];
        float mx = ss, sc[3];
        for (int j = 0; j < n; ++j) { sc[j] = leaky(u + fdot3[c0+j]); mx = fmaxf(mx, sc[j]); }
        float e0 = expf(ss - mx), s = e0, ec[3];
        for (int j = 0; j < n; ++j) { ec[j] = expf(sc[j] - mx); s += ec[j]; }
        const float inv = 1.f / s;
        ad0[p] = e0 * inv;
        float d5 = ad0[p] * ds[(1+p)*6 + 5];
        for (int j = 0; j < n; ++j) {
            const float a = ec[j] * inv;
            adc[c0+j] = a;
            d5 += a * fdot5[c0+j];
        }
        ddot5[p] = d5;
    }
    __syncthreads();

    if (tid == 0) {                       // level dr
        const float u = ds[0*6 + 4];
        const float ss = leaky(u + ds[0*6 + 5]);
        float mx = ss, sc[5];
#pragma unroll
        for (int d = 0; d < 5; ++d) { sc[d] = leaky(u + ddot5[d]); mx = fmaxf(mx, sc[d]); }
        float e0 = expf(ss - mx), s = e0, ec[5];
#pragma unroll
        for (int d = 0; d < 5; ++d) { ec[d] = expf(sc[d] - mx); s += ec[d]; }
        const float inv = 1.f / s;
        ar[0] = e0 * inv;
#pragma unroll
        for (int d = 0; d < 5; ++d) ar[1+d] = ec[d] * inv;
    }
    for (int q = tid; q < 36; q += 256) Ts[18+q][18+q] = 1.f;
    __syncthreads();

    if (tid < 54) {                       // domain rows
        const int j = tid;
        const int cstart[5] = {0,3,5,8,10};
        const int ccnt[5]   = {3,2,3,2,2};
        for (int p = 0; p < 5; ++p) {
            float t = ad0[p] * ((j == 1+p) ? 1.f : 0.f);
            for (int c = cstart[p]; c < cstart[p] + ccnt[p]; ++c) t += adc[c] * Ts[6+c][j];
            Ts[1+p][j] = t;
        }
    }
    __syncthreads();
    if (tid < 54) {                       // root row
        float t = ar[0] * ((tid == 0) ? 1.f : 0.f);
        for (int d = 0; d < 5; ++d) t += ar[1+d] * Ts[1+d][tid];
        Ts[0][tid] = t;
    }
    __syncthreads();
    for (int i = tid; i < 54 * 54; i += 256) Tm[i] = ((float*)Ts)[i];
}

// ---------------------------------------------------------------------------
// p5: fused applyT + rope. h2 rows on the fly (<=3 T-row dots per thread).
// grid (432): t = (jt 0..7) * 54 + r.
// ---------------------------------------------------------------------------
__global__ __launch_bounds__(256) void p5_g(const float* __restrict__ gsum,
                                            const float* __restrict__ Tm,
                                            const float* __restrict__ er,
                                            const float* __restrict__ ei,
                                            short* __restrict__ xh, short* __restrict__ xl,
                                            float* __restrict__ xo, int last)
{
    const int t   = blockIdx.x;
    const int tid = threadIdx.x;
    const int r  = t % 54;
    const int jt = t / 54;
    const int j  = jt * 256 + tid;          // 0..2047
    const int jj = j + 2048;
    constexpr int PF[12] = {0,0,0,1,1,2,2,2,3,3,4,4};

    int row1 = 0, row2 = 0;
    if (r >= 1 && r < 6)        { row1 = r; }
    else if (r >= 6 && r < 18)  { const int c = r - 6;      row1 = 1 + PF[c]; row2 = r; }
    else if (r >= 18)           { const int c = (r - 18)/3; row1 = 1 + PF[c]; row2 = 6 + c; }

    const float* T0 = Tm;
    const float* T1 = Tm + row1 * 54;
    const float* T2 = Tm + row2 * 54;

    float a0r=0,a0i=0,a1r=0,a1i=0,a2r=0,a2i=0;
#pragma unroll 6
    for (int k = 0; k < 54; ++k) {
        const float gr = gsum[(size_t)k * DIM + j];
        const float gi = gsum[(size_t)k * DIM + jj];
        const float t0 = T0[k], t1 = T1[k], t2 = T2[k];
        a0r += t0 * gr; a0i += t0 * gi;
        a1r += t1 * gr; a1i += t1 * gi;
        a2r += t2 * gr; a2i += t2 * gi;
    }

    const float rr = a0r, ri = a0i;
    float vr, vi, scale;
    if (r == 0) {
        vr = rr; vi = ri; scale = 1.f;
    } else {
        const float er0 = er[j], ei0 = ei[j];
        const float dr = a1r + rr * er0 - ri * ei0;
        const float di = a1i + rr * ei0 + ri * er0;
        if (r < 6) {
            vr = dr; vi = di; scale = 0.5f;
        } else {
            const float er1 = er[2048 + j], ei1 = ei[2048 + j];
            const float fr = a2r + dr * er1 - di * ei1;
            const float fi = a2i + dr * ei1 + di * er1;
            if (r < 18) {
                vr = fr; vi = fi; scale = 1.f / 3.f;
            } else {
                const float er2 = er[4096 + j], ei2 = ei[4096 + j];
                const float sr = gsum[(size_t)r * DIM + j];
                const float si = gsum[(size_t)r * DIM + jj];
                vr = sr + fr * er2 - fi * ei2;
                vi = si + fr * ei2 + fi * er2;
                scale = 0.25f;
            }
        }
    }
    vr *= scale; vi *= scale;
    if (last) {
        xo[(size_t)r * DIM + j]  = vr;
        xo[(size_t)r * DIM + jj] = vi;
    } else {
        const short h0 = f2bf(vr);
        xh[(size_t)r * DIM + j] = h0;
        xl[(size_t)r * DIM + j] = f2bf(vr - bf2f(h0));
        const short h1 = f2bf(vi);
        xh[(size_t)r * DIM + jj] = h1;
        xl[(size_t)r * DIM + jj] = f2bf(vi - bf2f(h1));
    }
}

// ---------------------------------------------------------------------------
extern "C" void kernel_launch(void* const* d_in, const int* in_sizes, int n_in,
                              void* d_out, int out_size, void* d_ws, size_t ws_size,
                              hipStream_t stream)
{
    const float* ce    = (const float*)d_in[0];
    const float* gatW  = (const float*)d_in[1];
    const float* attif = (const float*)d_in[2];
    const float* attfd = (const float*)d_in[3];
    const float* attdr = (const float*)d_in[4];
    const float* metaW = (const float*)d_in[5];
    const float* edge  = (const float*)d_in[6];
    float* out = (float*)d_out;

    char* w = (char*)d_ws;
    float* hpart = (float*)w;   w += (size_t)SPLITK * HSZ * 4;   // 14.2 MB
    float* gsum  = (float*)w;   w += (size_t)HSZ * 4;            // 884 KB
    float* dotp  = (float*)w;   w += 6144 * 4;                   // 864*6 used
    float* Tm    = (float*)w;   w += 16384;
    float* er    = (float*)w;   w += 3 * 2048 * 4;
    float* ei    = (float*)w;   w += 3 * 2048 * 4;
    short* xbfh  = (short*)w;   w += (size_t)64 * DIM * 2;       // 512 KB each
    short* xbfl  = (short*)w;   w += (size_t)64 * DIM * 2;
    short* hbfh  = (short*)w;   w += (size_t)64 * DIM * 2;
    short* hbfl  = (short*)w;   w += (size_t)64 * DIM * 2;

    hipLaunchKernelGGL(prep_g, dim3(1024), dim3(256), 0, stream,
                       ce, edge, xbfh, xbfl, hbfh, hbfl, er, ei);

    for (int i = 0; i < 4; ++i) {
        hipLaunchKernelGGL(gemm_g, dim3(1024), dim3(256), 0, stream,
                           xbfh, xbfl, gatW + (size_t)i * DIM * DIM, hpart);
        hipLaunchKernelGGL(p2_g, dim3(216), dim3(256), 0, stream,
                           hpart, attif + (size_t)i * 2 * DIM, attfd + (size_t)i * 2 * DIM,
                           attdr + (size_t)i * 2 * DIM, hbfh, hbfl, dotp);
        hipLaunchKernelGGL(tmat_g, dim3(1), dim3(256), 0, stream, dotp, Tm);
        hipLaunchKernelGGL(gemm_g, dim3(1024), dim3(256), 0, stream,
                           hbfh, hbfl, metaW + (size_t)i * DIM * DIM, hpart);
        hipLaunchKernelGGL(p4_g, dim3(216), dim3(256), 0, stream, hpart, gsum);
        hipLaunchKernelGGL(p5_g, dim3(432), dim3(256), 0, stream,
                           gsum, Tm, er, ei, xbfh, xbfl, out, (i == 3) ? 1 : 0);
    }
}

// Round 10
// 364.096 us; speedup vs baseline: 1.1589x; 1.1589x over previous
//
#include <hip/hip_runtime.h>
#include <hip/hip_bf16.h>

#define DIM 4096
#define HROWS 54
#define HSZ (54 * 4096)
#define SPLITK 16
#define KSLICE 256

typedef __attribute__((ext_vector_type(4))) float  f32x4;
typedef __attribute__((ext_vector_type(8))) short  s16x8;
typedef __attribute__((ext_vector_type(4))) short  s16x4;

__device__ __forceinline__ short f2bf(float f) {
    union { __hip_bfloat16 h; short s; } u;
    u.h = __float2bfloat16(f);
    return u.s;
}
__device__ __forceinline__ float bf2f(short s) {
    union { __hip_bfloat16 h; short s; } u;
    u.s = s;
    return __bfloat162float(u.h);
}
__device__ __forceinline__ float leaky(float x) { return x > 0.f ? x : 0.01f * x; }

__device__ __forceinline__ void split8(const f32x4& c0, const f32x4& c1,
                                       s16x8& h, s16x8& l) {
#pragma unroll
    for (int j = 0; j < 4; ++j) {
        short h0 = f2bf(c0[j]); h[j]     = h0; l[j]     = f2bf(c0[j] - bf2f(h0));
        short h1 = f2bf(c1[j]); h[4 + j] = h1; l[4 + j] = f2bf(c1[j] - bf2f(h1));
    }
}

// ---------------------------------------------------------------------------
// prep: bf16 split of concept_embed (padded to 64 rows), zero pads, trig tables
// ---------------------------------------------------------------------------
__global__ __launch_bounds__(256) void prep_g(const float* __restrict__ ce,
                                              const float* __restrict__ edge,
                                              short* __restrict__ xh, short* __restrict__ xl,
                                              short* __restrict__ hbh, short* __restrict__ hbl,
                                              float* __restrict__ er, float* __restrict__ ei)
{
    const int idx = blockIdx.x * 256 + threadIdx.x;
    const int row = idx >> 12;
    if (row < HROWS) {
        const float v = ce[idx];
        const short h = f2bf(v);
        xh[idx] = h; xl[idx] = f2bf(v - bf2f(h));
    } else {
        xh[idx] = 0; xl[idx] = 0; hbh[idx] = 0; hbl[idx] = 0;
    }
    if (idx < 3 * 2048) {
        const float e = edge[idx];
        er[idx] = cosf(e);
        ei[idx] = sinf(e);
    }
}

// ---------------------------------------------------------------------------
// GEMM v7: A-reuse x2. out[m,n] = sum_k A[m,k]*W[n,k].
// A bf16 hi/lo [64][4096] (L2-resident); W f32 streamed. Each wave computes
// TWO 16-col N-strips (ncolA, ncolA+64) sharing one set of A fragments ->
// per-CU A-side L2 traffic halves. Block covers BN=128 cols; grid =
// 32 nb x 16 ks = 512 blocks (2/CU). Plain loop; compiler schedules.
// ---------------------------------------------------------------------------
__global__ __launch_bounds__(256) void gemm_g(const short* __restrict__ Ah,
                                              const short* __restrict__ Al,
                                              const float* __restrict__ W,
                                              float* __restrict__ outp)
{
    const int tid  = threadIdx.x;
    const int lane = tid & 63;
    const int wv   = tid >> 6;
    const int nb   = blockIdx.x & 31;    // 0..31  (128-col tile)
    const int ks   = blockIdx.x >> 5;    // 0..15  (256-k slice)
    const int l15  = lane & 15;
    const int lk8  = lane >> 4;

    const int ncolA = nb * 128 + wv * 16 + l15;
    const int ncolB = ncolA + 64;
    const int k0    = ks * KSLICE + lk8 * 8;
    const float* wpA = W + (size_t)ncolA * DIM + k0;
    const float* wpB = W + (size_t)ncolB * DIM + k0;

    const short* ah0 = Ah + (size_t)(0*16 + l15) * DIM + k0;
    const short* ah1 = Ah + (size_t)(1*16 + l15) * DIM + k0;
    const short* ah2 = Ah + (size_t)(2*16 + l15) * DIM + k0;
    const short* ah3 = Ah + (size_t)(3*16 + l15) * DIM + k0;
    const short* al0 = Al + (size_t)(0*16 + l15) * DIM + k0;
    const short* al1 = Al + (size_t)(1*16 + l15) * DIM + k0;
    const short* al2 = Al + (size_t)(2*16 + l15) * DIM + k0;
    const short* al3 = Al + (size_t)(3*16 + l15) * DIM + k0;

    f32x4 accA0 = {0.f,0.f,0.f,0.f}, accA1 = {0.f,0.f,0.f,0.f};
    f32x4 accA2 = {0.f,0.f,0.f,0.f}, accA3 = {0.f,0.f,0.f,0.f};
    f32x4 accB0 = {0.f,0.f,0.f,0.f}, accB1 = {0.f,0.f,0.f,0.f};
    f32x4 accB2 = {0.f,0.f,0.f,0.f}, accB3 = {0.f,0.f,0.f,0.f};

#pragma unroll
    for (int kb = 0; kb < 4; ++kb) {
        const int ko = kb * 64;
        const f32x4 a00 = *(const f32x4*)(wpA + ko);
        const f32x4 a01 = *(const f32x4*)(wpA + ko + 4);
        const f32x4 a10 = *(const f32x4*)(wpA + ko + 32);
        const f32x4 a11 = *(const f32x4*)(wpA + ko + 36);
        const f32x4 b00 = *(const f32x4*)(wpB + ko);
        const f32x4 b01 = *(const f32x4*)(wpB + ko + 4);
        const f32x4 b10 = *(const f32x4*)(wpB + ko + 32);
        const f32x4 b11 = *(const f32x4*)(wpB + ko + 36);

#pragma unroll
        for (int kk = 0; kk < 2; ++kk) {
            s16x8 bhA, blA, bhB, blB;
            split8(kk ? a10 : a00, kk ? a11 : a01, bhA, blA);
            split8(kk ? b10 : b00, kk ? b11 : b01, bhB, blB);
            const int ao = ko + kk * 32;
            const s16x8 a0h = *(const s16x8*)(ah0 + ao);
            const s16x8 a1h = *(const s16x8*)(ah1 + ao);
            const s16x8 a2h = *(const s16x8*)(ah2 + ao);
            const s16x8 a3h = *(const s16x8*)(ah3 + ao);
            const s16x8 a0l = *(const s16x8*)(al0 + ao);
            const s16x8 a1l = *(const s16x8*)(al1 + ao);
            const s16x8 a2l = *(const s16x8*)(al2 + ao);
            const s16x8 a3l = *(const s16x8*)(al3 + ao);

            accA0 = __builtin_amdgcn_mfma_f32_16x16x32_bf16(a0h, bhA, accA0, 0, 0, 0);
            accA1 = __builtin_amdgcn_mfma_f32_16x16x32_bf16(a1h, bhA, accA1, 0, 0, 0);
            accA2 = __builtin_amdgcn_mfma_f32_16x16x32_bf16(a2h, bhA, accA2, 0, 0, 0);
            accA3 = __builtin_amdgcn_mfma_f32_16x16x32_bf16(a3h, bhA, accA3, 0, 0, 0);
            accA0 = __builtin_amdgcn_mfma_f32_16x16x32_bf16(a0l, bhA, accA0, 0, 0, 0);
            accA1 = __builtin_amdgcn_mfma_f32_16x16x32_bf16(a1l, bhA, accA1, 0, 0, 0);
            accA2 = __builtin_amdgcn_mfma_f32_16x16x32_bf16(a2l, bhA, accA2, 0, 0, 0);
            accA3 = __builtin_amdgcn_mfma_f32_16x16x32_bf16(a3l, bhA, accA3, 0, 0, 0);
            accA0 = __builtin_amdgcn_mfma_f32_16x16x32_bf16(a0h, blA, accA0, 0, 0, 0);
            accA1 = __builtin_amdgcn_mfma_f32_16x16x32_bf16(a1h, blA, accA1, 0, 0, 0);
            accA2 = __builtin_amdgcn_mfma_f32_16x16x32_bf16(a2h, blA, accA2, 0, 0, 0);
            accA3 = __builtin_amdgcn_mfma_f32_16x16x32_bf16(a3h, blA, accA3, 0, 0, 0);

            accB0 = __builtin_amdgcn_mfma_f32_16x16x32_bf16(a0h, bhB, accB0, 0, 0, 0);
            accB1 = __builtin_amdgcn_mfma_f32_16x16x32_bf16(a1h, bhB, accB1, 0, 0, 0);
            accB2 = __builtin_amdgcn_mfma_f32_16x16x32_bf16(a2h, bhB, accB2, 0, 0, 0);
            accB3 = __builtin_amdgcn_mfma_f32_16x16x32_bf16(a3h, bhB, accB3, 0, 0, 0);
            accB0 = __builtin_amdgcn_mfma_f32_16x16x32_bf16(a0l, bhB, accB0, 0, 0, 0);
            accB1 = __builtin_amdgcn_mfma_f32_16x16x32_bf16(a1l, bhB, accB1, 0, 0, 0);
            accB2 = __builtin_amdgcn_mfma_f32_16x16x32_bf16(a2l, bhB, accB2, 0, 0, 0);
            accB3 = __builtin_amdgcn_mfma_f32_16x16x32_bf16(a3l, bhB, accB3, 0, 0, 0);
            accB0 = __builtin_amdgcn_mfma_f32_16x16x32_bf16(a0h, blB, accB0, 0, 0, 0);
            accB1 = __builtin_amdgcn_mfma_f32_16x16x32_bf16(a1h, blB, accB1, 0, 0, 0);
            accB2 = __builtin_amdgcn_mfma_f32_16x16x32_bf16(a2h, blB, accB2, 0, 0, 0);
            accB3 = __builtin_amdgcn_mfma_f32_16x16x32_bf16(a3h, blB, accB3, 0, 0, 0);
        }
    }

    float* op = outp + (size_t)ks * HSZ;
#pragma unroll
    for (int mt = 0; mt < 4; ++mt) {
        const f32x4 a = (mt == 0) ? accA0 : (mt == 1) ? accA1 : (mt == 2) ? accA2 : accA3;
        const f32x4 b = (mt == 0) ? accB0 : (mt == 1) ? accB1 : (mt == 2) ? accB2 : accB3;
#pragma unroll
        for (int r = 0; r < 4; ++r) {
            const int m = mt * 16 + lk8 * 4 + r;
            if (m < HROWS) {
                op[(size_t)m * DIM + ncolA] = a[r];
                op[(size_t)m * DIM + ncolB] = b[r];
            }
        }
    }
}

// ---------------------------------------------------------------------------
// p2: reduce split-K partials -> bf16 hi/lo of h + fused attention-dot partials
// ---------------------------------------------------------------------------
__global__ __launch_bounds__(256) void p2_g(const float* __restrict__ hpart,
                                            const float* __restrict__ wA,
                                            const float* __restrict__ wB,
                                            const float* __restrict__ wC,
                                            short* __restrict__ hbh, short* __restrict__ hbl,
                                            float* __restrict__ dotp)
{
    const int vb  = blockIdx.x;          // 0..215
    const int tid = threadIdx.x;
    const int i   = vb * 1024 + tid * 4;
    const int col = i & (DIM - 1);
    f32x4 s = {0.f,0.f,0.f,0.f};
#pragma unroll
    for (int sl = 0; sl < SPLITK; ++sl) s += *(const f32x4*)(hpart + (size_t)sl * HSZ + i);

    s16x4 vh, vl;
#pragma unroll
    for (int j = 0; j < 4; ++j) {
        const short h = f2bf(s[j]);
        vh[j] = h; vl[j] = f2bf(s[j] - bf2f(h));
    }
    *(s16x4*)(hbh + i) = vh;
    *(s16x4*)(hbl + i) = vl;

    float a0=0,a1=0,a2=0,a3=0,a4=0,a5=0;
#pragma unroll
    for (int j = 0; j < 4; ++j) {
        const float sv = s[j];
        const int c = col + j;
        a0 += sv * wA[c]; a1 += sv * wA[DIM + c];
        a2 += sv * wB[c]; a3 += sv * wB[DIM + c];
        a4 += sv * wC[c]; a5 += sv * wC[DIM + c];
    }
#pragma unroll
    for (int off = 32; off > 0; off >>= 1) {
        a0 += __shfl_down(a0, off); a1 += __shfl_down(a1, off);
        a2 += __shfl_down(a2, off); a3 += __shfl_down(a3, off);
        a4 += __shfl_down(a4, off); a5 += __shfl_down(a5, off);
    }
    if ((tid & 63) == 0) {
        float* d = dotp + ((size_t)vb * 4 + (tid >> 6)) * 6;
        d[0]=a0; d[1]=a1; d[2]=a2; d[3]=a3; d[4]=a4; d[5]=a5;
    }
}

// ---------------------------------------------------------------------------
// p45: per-block {inline split-K reduce of its column set -> LDS, T rebuild,
// fused applyT + rope}. Block b owns 32 (j, j+2048) pairs = 64 columns.
// grid 64 x 256. Replaces p4 + tmat + p5 (launch-count cut).
// ---------------------------------------------------------------------------
__global__ __launch_bounds__(256) void p45_g(const float* __restrict__ hpart,
                                             const float* __restrict__ dotp,
                                             const float* __restrict__ er,
                                             const float* __restrict__ ei,
                                             short* __restrict__ xh, short* __restrict__ xl,
                                             float* __restrict__ xo, int last)
{
    const int b   = blockIdx.x;          // 0..63
    const int tid = threadIdx.x;
    __shared__ float gs[HROWS][64];      // gsum tile: col c<32 -> j=b*32+c, c>=32 -> jj
    __shared__ float ds[324];
    __shared__ float Ts[54][54];
    __shared__ float ad0[5], adc[12], ar[6], fdot3[12], fdot5[12], ddot5[5];

    // ---- phase 1: inline split-K reduce of this block's 54x64 gsum tile ----
    for (int x = tid; x < HROWS * 64; x += 256) {
        const int row = x >> 6;
        const int c   = x & 63;
        const int gj  = (c < 32) ? (b * 32 + c) : (2048 + b * 32 + (c - 32));
        float s = 0.f;
#pragma unroll
        for (int sl = 0; sl < SPLITK; ++sl)
            s += hpart[(size_t)sl * HSZ + (size_t)row * DIM + gj];
        gs[row][c] = s;
    }

    // ---- T build ----
    for (int x = tid; x < 324; x += 256) {
        const int r_ = x / 6, v = x % 6;
        float s = 0.f;
#pragma unroll
        for (int u = 0; u < 16; ++u) s += dotp[(size_t)(r_ * 16 + u) * 6 + v];
        ds[x] = s;
    }
    for (int i = tid; i < 54 * 54; i += 256) ((float*)Ts)[i] = 0.f;
    __syncthreads();

    if (tid < 12) {                       // level if
        const int p = tid;
        const float u = ds[(6+p)*6 + 0];
        const float ss = leaky(u + ds[(6+p)*6 + 1]);
        float sc[3], mx = ss;
#pragma unroll
        for (int j = 0; j < 3; ++j) { sc[j] = leaky(u + ds[(18+3*p+j)*6 + 1]); mx = fmaxf(mx, sc[j]); }
        float e0 = expf(ss - mx), s = e0, ec[3];
#pragma unroll
        for (int j = 0; j < 3; ++j) { ec[j] = expf(sc[j] - mx); s += ec[j]; }
        const float inv = 1.f / s;
        const float a0 = e0 * inv;
        float f3 = a0 * ds[(6+p)*6 + 3];
        float f5 = a0 * ds[(6+p)*6 + 5];
        Ts[6+p][6+p] = a0;
#pragma unroll
        for (int j = 0; j < 3; ++j) {
            const float a = ec[j] * inv;
            Ts[6+p][18+3*p+j] = a;
            f3 += a * ds[(18+3*p+j)*6 + 3];
            f5 += a * ds[(18+3*p+j)*6 + 5];
        }
        fdot3[p] = f3; fdot5[p] = f5;
    }
    __syncthreads();

    if (tid < 5) {                        // level fd
        const int p = tid;
        const int cstart[5] = {0,3,5,8,10};
        const int ccnt[5]   = {3,2,3,2,2};
        const float u = ds[(1+p)*6 + 2];
        const float ss = leaky(u + ds[(1+p)*6 + 3]);
        const int n = ccnt[p], c0 = cstart[p];
        float mx = ss, sc[3];
        for (int j = 0; j < n; ++j) { sc[j] = leaky(u + fdot3[c0+j]); mx = fmaxf(mx, sc[j]); }
        float e0 = expf(ss - mx), s = e0, ec[3];
        for (int j = 0; j < n; ++j) { ec[j] = expf(sc[j] - mx); s += ec[j]; }
        const float inv = 1.f / s;
        ad0[p] = e0 * inv;
        float d5 = ad0[p] * ds[(1+p)*6 + 5];
        for (int j = 0; j < n; ++j) {
            const float a = ec[j] * inv;
            adc[c0+j] = a;
            d5 += a * fdot5[c0+j];
        }
        ddot5[p] = d5;
    }
    __syncthreads();

    if (tid == 0) {                       // level dr
        const float u = ds[0*6 + 4];
        const float ss = leaky(u + ds[0*6 + 5]);
        float mx = ss, sc[5];
#pragma unroll
        for (int d = 0; d < 5; ++d) { sc[d] = leaky(u + ddot5[d]); mx = fmaxf(mx, sc[d]); }
        float e0 = expf(ss - mx), s = e0, ec[5];
#pragma unroll
        for (int d = 0; d < 5; ++d) { ec[d] = expf(sc[d] - mx); s += ec[d]; }
        const float inv = 1.f / s;
        ar[0] = e0 * inv;
#pragma unroll
        for (int d = 0; d < 5; ++d) ar[1+d] = ec[d] * inv;
    }
    for (int q = tid; q < 36; q += 256) Ts[18+q][18+q] = 1.f;
    __syncthreads();

    if (tid < 54) {                       // domain rows
        const int j = tid;
        const int cstart[5] = {0,3,5,8,10};
        const int ccnt[5]   = {3,2,3,2,2};
        for (int p = 0; p < 5; ++p) {
            float t = ad0[p] * ((j == 1+p) ? 1.f : 0.f);
            for (int c = cstart[p]; c < cstart[p] + ccnt[p]; ++c) t += adc[c] * Ts[6+c][j];
            Ts[1+p][j] = t;
        }
    }
    __syncthreads();
    if (tid < 54) {                       // root row
        float t = ar[0] * ((tid == 0) ? 1.f : 0.f);
        for (int d = 0; d < 5; ++d) t += ar[1+d] * Ts[1+d][tid];
        Ts[0][tid] = t;
    }
    __syncthreads();

    // ---- phase 2: fused applyT + rope, thread = (pair p, r-group rq) ----
    const int p  = tid & 31;             // pair index within block
    const int rq = tid >> 5;             // 0..7
    const int j  = b * 32 + p;           // 0..2047
    const int jj = j + 2048;
    constexpr int PF[12] = {0,0,0,1,1,2,2,2,3,3,4,4};

    const float er0 = er[j],        ei0 = ei[j];
    const float er1 = er[2048 + j], ei1 = ei[2048 + j];
    const float er2 = er[4096 + j], ei2 = ei[4096 + j];

    float a0r = 0.f, a0i = 0.f;
#pragma unroll 6
    for (int k = 0; k < HROWS; ++k) {
        const float t0 = Ts[0][k];
        a0r += t0 * gs[k][p];
        a0i += t0 * gs[k][p + 32];
    }
    const float rr = a0r, ri = a0i;

    for (int r = rq; r < HROWS; r += 8) {
        float vr, vi, scale;
        if (r == 0) {
            vr = rr; vi = ri; scale = 1.f;
        } else {
            int row1, row2 = 0;
            if (r < 6)       { row1 = r; }
            else if (r < 18) { const int c = r - 6;      row1 = 1 + PF[c]; row2 = r; }
            else             { const int c = (r - 18)/3; row1 = 1 + PF[c]; row2 = 6 + c; }

            float a1r = 0.f, a1i = 0.f;
#pragma unroll 6
            for (int k = 0; k < HROWS; ++k) {
                const float t1 = Ts[row1][k];
                a1r += t1 * gs[k][p];
                a1i += t1 * gs[k][p + 32];
            }
            const float dr = a1r + rr * er0 - ri * ei0;
            const float di = a1i + rr * ei0 + ri * er0;
            if (r < 6) {
                vr = dr; vi = di; scale = 0.5f;
            } else {
                float a2r = 0.f, a2i = 0.f;
#pragma unroll 6
                for (int k = 0; k < HROWS; ++k) {
                    const float t2 = Ts[row2][k];
                    a2r += t2 * gs[k][p];
                    a2i += t2 * gs[k][p + 32];
                }
                const float fr = a2r + dr * er1 - di * ei1;
                const float fi = a2i + dr * ei1 + di * er1;
                if (r < 18) {
                    vr = fr; vi = fi; scale = 1.f / 3.f;
                } else {
                    vr = gs[r][p]      + fr * er2 - fi * ei2;
                    vi = gs[r][p + 32] + fr * ei2 + fi * er2;
                    scale = 0.25f;
                }
            }
        }
        vr *= scale; vi *= scale;
        if (last) {
            xo[(size_t)r * DIM + j]  = vr;
            xo[(size_t)r * DIM + jj] = vi;
        } else {
            const short h0 = f2bf(vr);
            xh[(size_t)r * DIM + j] = h0;
            xl[(size_t)r * DIM + j] = f2bf(vr - bf2f(h0));
            const short h1 = f2bf(vi);
            xh[(size_t)r * DIM + jj] = h1;
            xl[(size_t)r * DIM + jj] = f2bf(vi - bf2f(h1));
        }
    }
}

// ---------------------------------------------------------------------------
extern "C" void kernel_launch(void* const* d_in, const int* in_sizes, int n_in,
                              void* d_out, int out_size, void* d_ws, size_t ws_size,
                              hipStream_t stream)
{
    const float* ce    = (const float*)d_in[0];
    const float* gatW  = (const float*)d_in[1];
    const float* attif = (const float*)d_in[2];
    const float* attfd = (const float*)d_in[3];
    const float* attdr = (const float*)d_in[4];
    const float* metaW = (const float*)d_in[5];
    const float* edge  = (const float*)d_in[6];
    float* out = (float*)d_out;

    char* w = (char*)d_ws;
    float* hpart = (float*)w;   w += (size_t)SPLITK * HSZ * 4;   // 14.2 MB
    float* dotp  = (float*)w;   w += 6144 * 4;                   // 864*6 used
    float* er    = (float*)w;   w += 3 * 2048 * 4;
    float* ei    = (float*)w;   w += 3 * 2048 * 4;
    short* xbfh  = (short*)w;   w += (size_t)64 * DIM * 2;       // 512 KB each
    short* xbfl  = (short*)w;   w += (size_t)64 * DIM * 2;
    short* hbfh  = (short*)w;   w += (size_t)64 * DIM * 2;
    short* hbfl  = (short*)w;   w += (size_t)64 * DIM * 2;

    hipLaunchKernelGGL(prep_g, dim3(1024), dim3(256), 0, stream,
                       ce, edge, xbfh, xbfl, hbfh, hbfl, er, ei);

    for (int i = 0; i < 4; ++i) {
        hipLaunchKernelGGL(gemm_g, dim3(512), dim3(256), 0, stream,
                           xbfh, xbfl, gatW + (size_t)i * DIM * DIM, hpart);
        hipLaunchKernelGGL(p2_g, dim3(216), dim3(256), 0, stream,
                           hpart, attif + (size_t)i * 2 * DIM, attfd + (size_t)i * 2 * DIM,
                           attdr + (size_t)i * 2 * DIM, hbfh, hbfl, dotp);
        hipLaunchKernelGGL(gemm_g, dim3(512), dim3(256), 0, stream,
                           hbfh, hbfl, metaW + (size_t)i * DIM * DIM, hpart);
        hipLaunchKernelGGL(p45_g, dim3(64), dim3(256), 0, stream,
                           hpart, dotp, er, ei, xbfh, xbfl, out, (i == 3) ? 1 : 0);
    }
}

// Round 11
// 258.613 us; speedup vs baseline: 1.6317x; 1.4079x over previous
//
#include <hip/hip_runtime.h>
#include <hip/hip_bf16.h>

#define DIM 4096
#define HROWS 54
#define HSZ (54 * 4096)
#define SPLITK 16
#define KSLICE 256

typedef __attribute__((ext_vector_type(4))) float  f32x4;
typedef __attribute__((ext_vector_type(8))) short  s16x8;
typedef __attribute__((ext_vector_type(4))) short  s16x4;

__device__ __forceinline__ short f2bf(float f) {
    union { __hip_bfloat16 h; short s; } u;
    u.h = __float2bfloat16(f);
    return u.s;
}
__device__ __forceinline__ float bf2f(short s) {
    union { __hip_bfloat16 h; short s; } u;
    u.s = s;
    return __bfloat162float(u.h);
}
__device__ __forceinline__ float leaky(float x) { return x > 0.f ? x : 0.01f * x; }

__device__ __forceinline__ void split8(const f32x4& c0, const f32x4& c1,
                                       s16x8& h, s16x8& l) {
#pragma unroll
    for (int j = 0; j < 4; ++j) {
        short h0 = f2bf(c0[j]); h[j]     = h0; l[j]     = f2bf(c0[j] - bf2f(h0));
        short h1 = f2bf(c1[j]); h[4 + j] = h1; l[4 + j] = f2bf(c1[j] - bf2f(h1));
    }
}

// ---------------------------------------------------------------------------
// prep: bf16 split of concept_embed (padded to 64 rows), zero pads, trig tables
// ---------------------------------------------------------------------------
__global__ __launch_bounds__(256) void prep_g(const float* __restrict__ ce,
                                              const float* __restrict__ edge,
                                              short* __restrict__ xh, short* __restrict__ xl,
                                              short* __restrict__ hbh, short* __restrict__ hbl,
                                              float* __restrict__ er, float* __restrict__ ei)
{
    const int idx = blockIdx.x * 256 + threadIdx.x;
    const int row = idx >> 12;
    if (row < HROWS) {
        const float v = ce[idx];
        const short h = f2bf(v);
        xh[idx] = h; xl[idx] = f2bf(v - bf2f(h));
    } else {
        xh[idx] = 0; xl[idx] = 0; hbh[idx] = 0; hbl[idx] = 0;
    }
    if (idx < 3 * 2048) {
        const float e = edge[idx];
        er[idx] = cosf(e);
        ei[idx] = sinf(e);
    }
}

// ---------------------------------------------------------------------------
// GEMM v8: A on lgkmcnt, W on vmcnt (queue separation).
// Stage the block's 64x256 A-slice (bf16 hi+lo, 64 KB) into LDS once
// (XOR-swizzled chunks, one barrier; staging vmcnt drains BEFORE any W load
// issues). Then the W stream is the only vmcnt user, issued in consumption
// order with 2-kb lookahead -> compiler emits counted vmcnt, never drains
// prefetch. A-reuse x2 (BN=128/block). grid = 32 nb x 16 ks = 512 blocks.
// ---------------------------------------------------------------------------
__global__ __launch_bounds__(256) void gemm_g(const short* __restrict__ Ah,
                                              const short* __restrict__ Al,
                                              const float* __restrict__ W,
                                              float* __restrict__ outp)
{
    __shared__ short lhi[64 * 256];   // 32 KB
    __shared__ short llo[64 * 256];   // 32 KB

    const int tid  = threadIdx.x;
    const int lane = tid & 63;
    const int wv   = tid >> 6;
    const int nb   = blockIdx.x & 31;    // 0..31  (128-col tile)
    const int ks   = blockIdx.x >> 5;    // 0..15  (256-k slice)
    const int l15  = lane & 15;
    const int lk8  = lane >> 4;
    const int koff = ks * KSLICE;

    // ---- stage A (hi/lo) into LDS, swizzled: chunk c of row r -> slot c^(r&7)
    for (int u = tid; u < 64 * 32; u += 256) {
        const int row  = u >> 5;
        const int c    = u & 31;
        const int slot = c ^ (row & 7);
        *(s16x8*)&lhi[row * 256 + slot * 8] =
            *(const s16x8*)(Ah + (size_t)row * DIM + koff + c * 8);
        *(s16x8*)&llo[row * 256 + slot * 8] =
            *(const s16x8*)(Al + (size_t)row * DIM + koff + c * 8);
    }
    __syncthreads();   // drains staging vmcnt+lgkm; W queue starts clean

    const int ncolA = nb * 128 + wv * 16 + l15;
    const int ncolB = ncolA + 64;
    const float* wpA = W + (size_t)ncolA * DIM + koff + lk8 * 8;
    const float* wpB = W + (size_t)ncolB * DIM + koff + lk8 * 8;

    f32x4 accA0 = {0.f,0.f,0.f,0.f}, accA1 = {0.f,0.f,0.f,0.f};
    f32x4 accA2 = {0.f,0.f,0.f,0.f}, accA3 = {0.f,0.f,0.f,0.f};
    f32x4 accB0 = {0.f,0.f,0.f,0.f}, accB1 = {0.f,0.f,0.f,0.f};
    f32x4 accB2 = {0.f,0.f,0.f,0.f}, accB3 = {0.f,0.f,0.f,0.f};

// W loads for one kb (both strips, both kk halves): 8 f32x4 = 32 VGPR
#define WLD(P, KB)                                                           \
    const f32x4 P##a0 = *(const f32x4*)(wpA + (KB)*64);                      \
    const f32x4 P##a1 = *(const f32x4*)(wpA + (KB)*64 + 4);                  \
    const f32x4 P##a2 = *(const f32x4*)(wpA + (KB)*64 + 32);                 \
    const f32x4 P##a3 = *(const f32x4*)(wpA + (KB)*64 + 36);                 \
    const f32x4 P##b0 = *(const f32x4*)(wpB + (KB)*64);                      \
    const f32x4 P##b1 = *(const f32x4*)(wpB + (KB)*64 + 4);                  \
    const f32x4 P##b2 = *(const f32x4*)(wpB + (KB)*64 + 32);                 \
    const f32x4 P##b3 = *(const f32x4*)(wpB + (KB)*64 + 36);

// one (kb,kk) unit: 8 ds_read_b128 A frags + 24 MFMA (2 strips share A)
#define CKK(WA0, WA1, WB0, WB1, KB, KK)                                      \
    {   const int sl_ = (((KB)*8 + (KK)*4 + lk8) ^ (l15 & 7)) * 8;           \
        const s16x8 a0h = *(const s16x8*)&lhi[( 0 + l15)*256 + sl_];         \
        const s16x8 a1h = *(const s16x8*)&lhi[(16 + l15)*256 + sl_];         \
        const s16x8 a2h = *(const s16x8*)&lhi[(32 + l15)*256 + sl_];         \
        const s16x8 a3h = *(const s16x8*)&lhi[(48 + l15)*256 + sl_];         \
        const s16x8 a0l = *(const s16x8*)&llo[( 0 + l15)*256 + sl_];         \
        const s16x8 a1l = *(const s16x8*)&llo[(16 + l15)*256 + sl_];         \
        const s16x8 a2l = *(const s16x8*)&llo[(32 + l15)*256 + sl_];         \
        const s16x8 a3l = *(const s16x8*)&llo[(48 + l15)*256 + sl_];         \
        s16x8 bhA, blA, bhB, blB;                                            \
        split8(WA0, WA1, bhA, blA);                                          \
        split8(WB0, WB1, bhB, blB);                                          \
        accA0 = __builtin_amdgcn_mfma_f32_16x16x32_bf16(a0h, bhA, accA0, 0, 0, 0); \
        accA1 = __builtin_amdgcn_mfma_f32_16x16x32_bf16(a1h, bhA, accA1, 0, 0, 0); \
        accA2 = __builtin_amdgcn_mfma_f32_16x16x32_bf16(a2h, bhA, accA2, 0, 0, 0); \
        accA3 = __builtin_amdgcn_mfma_f32_16x16x32_bf16(a3h, bhA, accA3, 0, 0, 0); \
        accA0 = __builtin_amdgcn_mfma_f32_16x16x32_bf16(a0l, bhA, accA0, 0, 0, 0); \
        accA1 = __builtin_amdgcn_mfma_f32_16x16x32_bf16(a1l, bhA, accA1, 0, 0, 0); \
        accA2 = __builtin_amdgcn_mfma_f32_16x16x32_bf16(a2l, bhA, accA2, 0, 0, 0); \
        accA3 = __builtin_amdgcn_mfma_f32_16x16x32_bf16(a3l, bhA, accA3, 0, 0, 0); \
        accA0 = __builtin_amdgcn_mfma_f32_16x16x32_bf16(a0h, blA, accA0, 0, 0, 0); \
        accA1 = __builtin_amdgcn_mfma_f32_16x16x32_bf16(a1h, blA, accA1, 0, 0, 0); \
        accA2 = __builtin_amdgcn_mfma_f32_16x16x32_bf16(a2h, blA, accA2, 0, 0, 0); \
        accA3 = __builtin_amdgcn_mfma_f32_16x16x32_bf16(a3h, blA, accA3, 0, 0, 0); \
        accB0 = __builtin_amdgcn_mfma_f32_16x16x32_bf16(a0h, bhB, accB0, 0, 0, 0); \
        accB1 = __builtin_amdgcn_mfma_f32_16x16x32_bf16(a1h, bhB, accB1, 0, 0, 0); \
        accB2 = __builtin_amdgcn_mfma_f32_16x16x32_bf16(a2h, bhB, accB2, 0, 0, 0); \
        accB3 = __builtin_amdgcn_mfma_f32_16x16x32_bf16(a3h, bhB, accB3, 0, 0, 0); \
        accB0 = __builtin_amdgcn_mfma_f32_16x16x32_bf16(a0l, bhB, accB0, 0, 0, 0); \
        accB1 = __builtin_amdgcn_mfma_f32_16x16x32_bf16(a1l, bhB, accB1, 0, 0, 0); \
        accB2 = __builtin_amdgcn_mfma_f32_16x16x32_bf16(a2l, bhB, accB2, 0, 0, 0); \
        accB3 = __builtin_amdgcn_mfma_f32_16x16x32_bf16(a3l, bhB, accB3, 0, 0, 0); \
        accB0 = __builtin_amdgcn_mfma_f32_16x16x32_bf16(a0h, blB, accB0, 0, 0, 0); \
        accB1 = __builtin_amdgcn_mfma_f32_16x16x32_bf16(a1h, blB, accB1, 0, 0, 0); \
        accB2 = __builtin_amdgcn_mfma_f32_16x16x32_bf16(a2h, blB, accB2, 0, 0, 0); \
        accB3 = __builtin_amdgcn_mfma_f32_16x16x32_bf16(a3h, blB, accB3, 0, 0, 0); }

    // W issued in consumption order, 2-kb lookahead; A all via LDS (lgkm)
    WLD(w0_, 0) WLD(w1_, 1)
    CKK(w0_a0, w0_a1, w0_b0, w0_b1, 0, 0)
    CKK(w0_a2, w0_a3, w0_b2, w0_b3, 0, 1)
    WLD(w2_, 2)
    CKK(w1_a0, w1_a1, w1_b0, w1_b1, 1, 0)
    CKK(w1_a2, w1_a3, w1_b2, w1_b3, 1, 1)
    WLD(w3_, 3)
    CKK(w2_a0, w2_a1, w2_b0, w2_b1, 2, 0)
    CKK(w2_a2, w2_a3, w2_b2, w2_b3, 2, 1)
    CKK(w3_a0, w3_a1, w3_b0, w3_b1, 3, 0)
    CKK(w3_a2, w3_a3, w3_b2, w3_b3, 3, 1)

#undef WLD
#undef CKK

    float* op = outp + (size_t)ks * HSZ;
#pragma unroll
    for (int mt = 0; mt < 4; ++mt) {
        const f32x4 a = (mt == 0) ? accA0 : (mt == 1) ? accA1 : (mt == 2) ? accA2 : accA3;
        const f32x4 b = (mt == 0) ? accB0 : (mt == 1) ? accB1 : (mt == 2) ? accB2 : accB3;
#pragma unroll
        for (int r = 0; r < 4; ++r) {
            const int m = mt * 16 + lk8 * 4 + r;
            if (m < HROWS) {
                op[(size_t)m * DIM + ncolA] = a[r];
                op[(size_t)m * DIM + ncolB] = b[r];
            }
        }
    }
}

// ---------------------------------------------------------------------------
// p2: reduce split-K partials -> bf16 hi/lo of h + fused attention-dot partials
// ---------------------------------------------------------------------------
__global__ __launch_bounds__(256) void p2_g(const float* __restrict__ hpart,
                                            const float* __restrict__ wA,
                                            const float* __restrict__ wB,
                                            const float* __restrict__ wC,
                                            short* __restrict__ hbh, short* __restrict__ hbl,
                                            float* __restrict__ dotp)
{
    const int vb  = blockIdx.x;          // 0..215
    const int tid = threadIdx.x;
    const int i   = vb * 1024 + tid * 4;
    const int col = i & (DIM - 1);
    f32x4 s = {0.f,0.f,0.f,0.f};
#pragma unroll
    for (int sl = 0; sl < SPLITK; ++sl) s += *(const f32x4*)(hpart + (size_t)sl * HSZ + i);

    s16x4 vh, vl;
#pragma unroll
    for (int j = 0; j < 4; ++j) {
        const short h = f2bf(s[j]);
        vh[j] = h; vl[j] = f2bf(s[j] - bf2f(h));
    }
    *(s16x4*)(hbh + i) = vh;
    *(s16x4*)(hbl + i) = vl;

    float a0=0,a1=0,a2=0,a3=0,a4=0,a5=0;
#pragma unroll
    for (int j = 0; j < 4; ++j) {
        const float sv = s[j];
        const int c = col + j;
        a0 += sv * wA[c]; a1 += sv * wA[DIM + c];
        a2 += sv * wB[c]; a3 += sv * wB[DIM + c];
        a4 += sv * wC[c]; a5 += sv * wC[DIM + c];
    }
#pragma unroll
    for (int off = 32; off > 0; off >>= 1) {
        a0 += __shfl_down(a0, off); a1 += __shfl_down(a1, off);
        a2 += __shfl_down(a2, off); a3 += __shfl_down(a3, off);
        a4 += __shfl_down(a4, off); a5 += __shfl_down(a5, off);
    }
    if ((tid & 63) == 0) {
        float* d = dotp + ((size_t)vb * 4 + (tid >> 6)) * 6;
        d[0]=a0; d[1]=a1; d[2]=a2; d[3]=a3; d[4]=a4; d[5]=a5;
    }
}

// ---------------------------------------------------------------------------
// p45: per-block {inline split-K reduce of its 8 column-pairs -> LDS,
// T rebuild, fused applyT + rope}. grid 256 x 256 (full-CU spread).
// ---------------------------------------------------------------------------
__global__ __launch_bounds__(256) void p45_g(const float* __restrict__ hpart,
                                             const float* __restrict__ dotp,
                                             const float* __restrict__ er,
                                             const float* __restrict__ ei,
                                             short* __restrict__ xh, short* __restrict__ xl,
                                             float* __restrict__ xo, int last)
{
    const int b   = blockIdx.x;          // 0..255
    const int tid = threadIdx.x;
    __shared__ float gs[HROWS][16];      // c<8 -> j=b*8+c, c>=8 -> jj
    __shared__ float ds[324];
    __shared__ float Ts[54][54];
    __shared__ float ad0[5], adc[12], ar[6], fdot3[12], fdot5[12], ddot5[5];

    // ---- phase 1: inline split-K reduce of this block's 54x16 gsum tile ----
    for (int x = tid; x < HROWS * 16; x += 256) {
        const int row = x >> 4;
        const int c   = x & 15;
        const int gj  = (c < 8) ? (b * 8 + c) : (2048 + b * 8 + (c - 8));
        float s = 0.f;
#pragma unroll
        for (int sl = 0; sl < SPLITK; ++sl)
            s += hpart[(size_t)sl * HSZ + (size_t)row * DIM + gj];
        gs[row][c] = s;
    }

    // ---- T build ----
    for (int x = tid; x < 324; x += 256) {
        const int r_ = x / 6, v = x % 6;
        float s = 0.f;
#pragma unroll
        for (int u = 0; u < 16; ++u) s += dotp[(size_t)(r_ * 16 + u) * 6 + v];
        ds[x] = s;
    }
    for (int i = tid; i < 54 * 54; i += 256) ((float*)Ts)[i] = 0.f;
    __syncthreads();

    if (tid < 12) {                       // level if
        const int p = tid;
        const float u = ds[(6+p)*6 + 0];
        const float ss = leaky(u + ds[(6+p)*6 + 1]);
        float sc[3], mx = ss;
#pragma unroll
        for (int j = 0; j < 3; ++j) { sc[j] = leaky(u + ds[(18+3*p+j)*6 + 1]); mx = fmaxf(mx, sc[j]); }
        float e0 = expf(ss - mx), s = e0, ec[3];
#pragma unroll
        for (int j = 0; j < 3; ++j) { ec[j] = expf(sc[j] - mx); s += ec[j]; }
        const float inv = 1.f / s;
        const float a0 = e0 * inv;
        float f3 = a0 * ds[(6+p)*6 + 3];
        float f5 = a0 * ds[(6+p)*6 + 5];
        Ts[6+p][6+p] = a0;
#pragma unroll
        for (int j = 0; j < 3; ++j) {
            const float a = ec[j] * inv;
            Ts[6+p][18+3*p+j] = a;
            f3 += a * ds[(18+3*p+j)*6 + 3];
            f5 += a * ds[(18+3*p+j)*6 + 5];
        }
        fdot3[p] = f3; fdot5[p] = f5;
    }
    __syncthreads();

    if (tid < 5) {                        // level fd
        const int p = tid;
        const int cstart[5] = {0,3,5,8,10};
        const int ccnt[5]   = {3,2,3,2,2};
        const float u = ds[(1+p)*6 + 2];
        const float ss = leaky(u + ds[(1+p)*6 + 3]);
        const int n = ccnt[p], c0 = cstart[p];
        float mx = ss, sc[3];
        for (int j = 0; j < n; ++j) { sc[j] = leaky(u + fdot3[c0+j]); mx = fmaxf(mx, sc[j]); }
        float e0 = expf(ss - mx), s = e0, ec[3];
        for (int j = 0; j < n; ++j) { ec[j] = expf(sc[j] - mx); s += ec[j]; }
        const float inv = 1.f / s;
        ad0[p] = e0 * inv;
        float d5 = ad0[p] * ds[(1+p)*6 + 5];
        for (int j = 0; j < n; ++j) {
            const float a = ec[j] * inv;
            adc[c0+j] = a;
            d5 += a * fdot5[c0+j];
        }
        ddot5[p] = d5;
    }
    __syncthreads();

    if (tid == 0) {                       // level dr
        const float u = ds[0*6 + 4];
        const float ss = leaky(u + ds[0*6 + 5]);
        float mx = ss, sc[5];
#pragma unroll
        for (int d = 0; d < 5; ++d) { sc[d] = leaky(u + ddot5[d]); mx = fmaxf(mx, sc[d]); }
        float e0 = expf(ss - mx), s = e0, ec[5];
#pragma unroll
        for (int d = 0; d < 5; ++d) { ec[d] = expf(sc[d] - mx); s += ec[d]; }
        const float inv = 1.f / s;
        ar[0] = e0 * inv;
#pragma unroll
        for (int d = 0; d < 5; ++d) ar[1+d] = ec[d] * inv;
    }
    for (int q = tid; q < 36; q += 256) Ts[18+q][18+q] = 1.f;
    __syncthreads();

    if (tid < 54) {                       // domain rows
        const int j = tid;
        const int cstart[5] = {0,3,5,8,10};
        const int ccnt[5]   = {3,2,3,2,2};
        for (int p = 0; p < 5; ++p) {
            float t = ad0[p] * ((j == 1+p) ? 1.f : 0.f);
            for (int c = cstart[p]; c < cstart[p] + ccnt[p]; ++c) t += adc[c] * Ts[6+c][j];
            Ts[1+p][j] = t;
        }
    }
    __syncthreads();
    if (tid < 54) {                       // root row
        float t = ar[0] * ((tid == 0) ? 1.f : 0.f);
        for (int d = 0; d < 5; ++d) t += ar[1+d] * Ts[1+d][tid];
        Ts[0][tid] = t;
    }
    __syncthreads();

    // ---- phase 2: fused applyT + rope; thread = (pair p, r-group rq) ----
    const int p  = tid & 7;              // pair index within block
    const int rq = tid >> 3;             // 0..31
    const int j  = b * 8 + p;            // 0..2047
    const int jj = j + 2048;
    constexpr int PF[12] = {0,0,0,1,1,2,2,2,3,3,4,4};

    const float er0 = er[j],        ei0 = ei[j];
    const float er1 = er[2048 + j], ei1 = ei[2048 + j];
    const float er2 = er[4096 + j], ei2 = ei[4096 + j];

    float a0r = 0.f, a0i = 0.f;
#pragma unroll 6
    for (int k = 0; k < HROWS; ++k) {
        const float t0 = Ts[0][k];
        a0r += t0 * gs[k][p];
        a0i += t0 * gs[k][p + 8];
    }
    const float rr = a0r, ri = a0i;

    for (int r = rq; r < HROWS; r += 32) {
        float vr, vi, scale;
        if (r == 0) {
            vr = rr; vi = ri; scale = 1.f;
        } else {
            int row1, row2 = 0;
            if (r < 6)       { row1 = r; }
            else if (r < 18) { const int c = r - 6;      row1 = 1 + PF[c]; row2 = r; }
            else             { const int c = (r - 18)/3; row1 = 1 + PF[c]; row2 = 6 + c; }

            float a1r = 0.f, a1i = 0.f;
#pragma unroll 6
            for (int k = 0; k < HROWS; ++k) {
                const float t1 = Ts[row1][k];
                a1r += t1 * gs[k][p];
                a1i += t1 * gs[k][p + 8];
            }
            const float dr = a1r + rr * er0 - ri * ei0;
            const float di = a1i + rr * ei0 + ri * er0;
            if (r < 6) {
                vr = dr; vi = di; scale = 0.5f;
            } else {
                float a2r = 0.f, a2i = 0.f;
#pragma unroll 6
                for (int k = 0; k < HROWS; ++k) {
                    const float t2 = Ts[row2][k];
                    a2r += t2 * gs[k][p];
                    a2i += t2 * gs[k][p + 8];
                }
                const float fr = a2r + dr * er1 - di * ei1;
                const float fi = a2i + dr * ei1 + di * er1;
                if (r < 18) {
                    vr = fr; vi = fi; scale = 1.f / 3.f;
                } else {
                    vr = gs[r][p]     + fr * er2 - fi * ei2;
                    vi = gs[r][p + 8] + fr * ei2 + fi * er2;
                    scale = 0.25f;
                }
            }
        }
        vr *= scale; vi *= scale;
        if (last) {
            xo[(size_t)r * DIM + j]  = vr;
            xo[(size_t)r * DIM + jj] = vi;
        } else {
            const short h0 = f2bf(vr);
            xh[(size_t)r * DIM + j] = h0;
            xl[(size_t)r * DIM + j] = f2bf(vr - bf2f(h0));
            const short h1 = f2bf(vi);
            xh[(size_t)r * DIM + jj] = h1;
            xl[(size_t)r * DIM + jj] = f2bf(vi - bf2f(h1));
        }
    }
}

// ---------------------------------------------------------------------------
extern "C" void kernel_launch(void* const* d_in, const int* in_sizes, int n_in,
                              void* d_out, int out_size, void* d_ws, size_t ws_size,
                              hipStream_t stream)
{
    const float* ce    = (const float*)d_in[0];
    const float* gatW  = (const float*)d_in[1];
    const float* attif = (const float*)d_in[2];
    const float* attfd = (const float*)d_in[3];
    const float* attdr = (const float*)d_in[4];
    const float* metaW = (const float*)d_in[5];
    const float* edge  = (const float*)d_in[6];
    float* out = (float*)d_out;

    char* w = (char*)d_ws;
    float* hpart = (float*)w;   w += (size_t)SPLITK * HSZ * 4;   // 14.2 MB
    float* dotp  = (float*)w;   w += 6144 * 4;                   // 864*6 used
    float* er    = (float*)w;   w += 3 * 2048 * 4;
    float* ei    = (float*)w;   w += 3 * 2048 * 4;
    short* xbfh  = (short*)w;   w += (size_t)64 * DIM * 2;       // 512 KB each
    short* xbfl  = (short*)w;   w += (size_t)64 * DIM * 2;
    short* hbfh  = (short*)w;   w += (size_t)64 * DIM * 2;
    short* hbfl  = (short*)w;   w += (size_t)64 * DIM * 2;

    hipLaunchKernelGGL(prep_g, dim3(1024), dim3(256), 0, stream,
                       ce, edge, xbfh, xbfl, hbfh, hbfl, er, ei);

    for (int i = 0; i < 4; ++i) {
        hipLaunchKernelGGL(gemm_g, dim3(512), dim3(256), 0, stream,
                           xbfh, xbfl, gatW + (size_t)i * DIM * DIM, hpart);
        hipLaunchKernelGGL(p2_g, dim3(216), dim3(256), 0, stream,
                           hpart, attif + (size_t)i * 2 * DIM, attfd + (size_t)i * 2 * DIM,
                           attdr + (size_t)i * 2 * DIM, hbfh, hbfl, dotp);
        hipLaunchKernelGGL(gemm_g, dim3(512), dim3(256), 0, stream,
                           hbfh, hbfl, metaW + (size_t)i * DIM * DIM, hpart);
        hipLaunchKernelGGL(p45_g, dim3(256), dim3(256), 0, stream,
                           hpart, dotp, er, ei, xbfh, xbfl, out, (i == 3) ? 1 : 0);
    }
}